// Round 8
// baseline (94.778 us; speedup 1.0000x reference)
//
#include <hip/hip_runtime.h>
#include <math.h>

#define NJ 7
#define DTF 0.01f
#define GRAVF 9.81f
#define MIX(i,j) ((i)*((i)+1)/2 + (j))
#define MPAD 29   // 28 lower-tri floats padded to 29
#define CW 28     // const floats per joint (7 x float4)

// Per-joint constant block at cst + j*CW (16B-aligned):
// [0:9)  Rt (row-major)  [9:12) a  [12:15) p  [15] pad
// [16:22) SA = (A00,A01,A02,A11,A12,A22)  [22:25) h  [25] m  [26:28) pad

__device__ __forceinline__ void cross3(const float* a, const float* b, float* o){
    o[0] = a[1]*b[2] - a[2]*b[1];
    o[1] = a[2]*b[0] - a[0]*b[2];
    o[2] = a[0]*b[1] - a[1]*b[0];
}
__device__ __forceinline__ void mv3(const float* E, const float* x, float* y){
    y[0] = E[0]*x[0] + E[1]*x[1] + E[2]*x[2];
    y[1] = E[3]*x[0] + E[4]*x[1] + E[5]*x[2];
    y[2] = E[6]*x[0] + E[7]*x[1] + E[8]*x[2];
}
__device__ __forceinline__ void mtv3(const float* E, const float* x, float* y){
    y[0] = E[0]*x[0] + E[3]*x[1] + E[6]*x[2];
    y[1] = E[1]*x[0] + E[4]*x[1] + E[7]*x[2];
    y[2] = E[2]*x[0] + E[5]*x[1] + E[8]*x[2];
}
__device__ __forceinline__ void symv(const float* S, const float* x, float* y){
    y[0] = S[0]*x[0] + S[1]*x[1] + S[2]*x[2];
    y[1] = S[1]*x[0] + S[3]*x[1] + S[4]*x[2];
    y[2] = S[2]*x[0] + S[4]*x[1] + S[5]*x[2];
}
__device__ __forceinline__ void mm3(const float* A, const float* B, float* o){
#pragma unroll
    for (int r = 0; r < 3; r++)
#pragma unroll
        for (int c = 0; c < 3; c++)
            o[r*3+c] = A[r*3]*B[c] + A[r*3+1]*B[3+c] + A[r*3+2]*B[6+c];
}
__device__ __forceinline__ void congr(const float* E, const float* X, float* o){
    float t[9];
#pragma unroll
    for (int r = 0; r < 3; r++)
#pragma unroll
        for (int c = 0; c < 3; c++)
            t[r*3+c] = E[r]*X[c] + E[3+r]*X[3+c] + E[6+r]*X[6+c];
    mm3(t, E, o);
}
__device__ __forceinline__ void makeE(const float* a, const float* Rt, float s, float c, float* E){
    float omc = 1.0f - c;
    float RT[9];
    RT[0] = c + omc*a[0]*a[0];       RT[1] =  s*a[2] + omc*a[0]*a[1]; RT[2] = -s*a[1] + omc*a[0]*a[2];
    RT[3] = -s*a[2] + omc*a[1]*a[0]; RT[4] = c + omc*a[1]*a[1];       RT[5] =  s*a[0] + omc*a[1]*a[2];
    RT[6] =  s*a[1] + omc*a[2]*a[0]; RT[7] = -s*a[0] + omc*a[2]*a[1]; RT[8] = c + omc*a[2]*a[2];
    mm3(RT, Rt, E);
}
__device__ __forceinline__ void loadJ(const float* __restrict__ cst, int i,
                                      float* Rt, float* a, float* p,
                                      float* SA, float* h, float& m){
    const float4* cb4 = (const float4*)(cst + i*CW);
    float4 c0=cb4[0], c1=cb4[1], c2=cb4[2], c3=cb4[3], c4=cb4[4], c5=cb4[5], c6=cb4[6];
    Rt[0]=c0.x; Rt[1]=c0.y; Rt[2]=c0.z; Rt[3]=c0.w;
    Rt[4]=c1.x; Rt[5]=c1.y; Rt[6]=c1.z; Rt[7]=c1.w;
    Rt[8]=c2.x; a[0]=c2.y; a[1]=c2.z; a[2]=c2.w;
    p[0]=c3.x; p[1]=c3.y; p[2]=c3.z;
    SA[0]=c4.x; SA[1]=c4.y; SA[2]=c4.z; SA[3]=c4.w;
    SA[4]=c5.x; SA[5]=c5.y; h[0]=c5.z; h[1]=c5.w;
    h[2]=c6.x; m=c6.y;
}
__device__ __forceinline__ void loadG(const float* __restrict__ cst, int i,
                                      float* Rt, float* a, float* p){
    const float4* cb4 = (const float4*)(cst + i*CW);
    float4 c0=cb4[0], c1=cb4[1], c2=cb4[2], c3=cb4[3];
    Rt[0]=c0.x; Rt[1]=c0.y; Rt[2]=c0.z; Rt[3]=c0.w;
    Rt[4]=c1.x; Rt[5]=c1.y; Rt[6]=c1.z; Rt[7]=c1.w;
    Rt[8]=c2.x; a[0]=c2.y; a[1]=c2.z; a[2]=c2.w;
    p[0]=c3.x; p[1]=c3.y; p[2]=c3.z;
}
__device__ __forceinline__ void loadI(const float* __restrict__ cst, int i,
                                      float* SA, float* h, float& m){
    const float4* cb4 = (const float4*)(cst + i*CW);
    float4 c4=cb4[4], c5=cb4[5], c6=cb4[6];
    SA[0]=c4.x; SA[1]=c4.y; SA[2]=c4.z; SA[3]=c4.w;
    SA[4]=c5.x; SA[5]=c5.y; h[0]=c5.z; h[1]=c5.w;
    h[2]=c6.x; m=c6.y;
}

__constant__ float QL_c[NJ] = {-2.9671f,-1.8326f,-2.9671f,-3.1416f,-2.9671f,-0.0873f,-2.9671f};
__constant__ float QU_c[NJ] = { 2.9671f, 1.8326f, 2.9671f, 0.0f,    2.9671f, 3.8223f, 2.9671f};

__global__ void panda_prep(const float* __restrict__ g_ax, const float* __restrict__ g_Rt,
                           const float* __restrict__ g_pt, const float* __restrict__ g_I,
                           float* __restrict__ cst)
{
    int i = threadIdx.x;
    if (i >= NJ) return;
    float* o = cst + i*CW;
#pragma unroll
    for (int k = 0; k < 9; k++) o[k] = g_Rt[i*9+k];
    o[9]=g_ax[i*3]; o[10]=g_ax[i*3+1]; o[11]=g_ax[i*3+2];
    o[12]=g_pt[i*3]; o[13]=g_pt[i*3+1]; o[14]=g_pt[i*3+2]; o[15]=0.f;
    const float* I6 = g_I + i*36;
    o[16]=I6[0];  o[17]=I6[1];  o[18]=I6[2];
    o[19]=I6[7];  o[20]=I6[8];  o[21]=I6[14];
    o[22]=I6[16]; o[23]=I6[5];  o[24]=I6[9];
    o[25]=I6[21]; o[26]=0.f; o[27]=0.f;
}

// Block = 128 = 2 waves on the SAME 64 elements.
// Wave 0: RNEA bias -> rhs; after sync: triangular solves + integrate + store.
// Wave 1: CRBA -> Cholesky factor -> LDS.
// Low-register variant: E is never stored across passes (recomputed from sn/cs).
__global__ __launch_bounds__(128, 3)
void panda_step(const float* __restrict__ x, const float* __restrict__ u,
                const float* __restrict__ cst, float* __restrict__ out, int B)
{
    __shared__ float s_M[64*MPAD];

    const int role = threadIdx.x >> 6;      // wave-uniform
    const int lane = threadIdx.x & 63;
    const int e    = blockIdx.x*64 + lane;
    const bool act = (e < B);

    float q[NJ], qd[NJ], sn[NJ], cs[NJ];
    if (act){
        float xl[14];
        const float2* x2 = (const float2*)(x + e*14);
#pragma unroll
        for (int i = 0; i < 7; i++){ float2 v = x2[i]; xl[2*i] = v.x; xl[2*i+1] = v.y; }
#pragma unroll
        for (int i = 0; i < NJ; i++){
            float qi = fminf(fmaxf(xl[i], QL_c[i]), QU_c[i]);
            __sincosf(qi, &sn[i], &cs[i]);
            if (role == 0){ q[i] = qi; qd[i] = xl[NJ + i]; }
        }
    }

    float rhs[NJ];

    if (act && role == 1){
        // =================== CRBA + Cholesky factor ===================
        float SA[6], hc[3], mc;
        { float dm; loadI(cst, 6, SA, hc, dm); mc = dm; }
        float Fk[NJ][6];
        float Mx[28];
#pragma unroll
        for (int i = NJ-1; i >= 0; i--){
            float Rt[9], a[3], p[3];
            loadG(cst, i, Rt, a, p);
            float SAm[6], hm[3], mm_;
            if (i > 0) loadI(cst, i-1, SAm, hm, mm_);
            // F_i = Ic @ S_i = [A a ; a x h]
            symv(SA, a, &Fk[i][0]);
            Fk[i][3] = a[1]*hc[2] - a[2]*hc[1];
            Fk[i][4] = a[2]*hc[0] - a[0]*hc[2];
            Fk[i][5] = a[0]*hc[1] - a[1]*hc[0];
#pragma unroll
            for (int k = i; k < NJ; k++)
                Mx[MIX(k,i)] = a[0]*Fk[k][0] + a[1]*Fk[k][1] + a[2]*Fk[k][2];
            if (i > 0){
                float E[9]; makeE(a, Rt, sn[i], cs[i], E);
                float Af[9] = {SA[0],SA[1],SA[2], SA[1],SA[3],SA[4], SA[2],SA[4],SA[5]};
                float Ap[9]; congr(E, Af, Ap);
                float hr[3]; mtv3(E, hc, hr);
                float hpd = hr[0]*p[0]+hr[1]*p[1]+hr[2]*p[2];
                float ppd = p[0]*p[0]+p[1]*p[1]+p[2]*p[2];
                float dga = 2.0f*hpd + mc*ppd;
                SA[0] = Ap[0] - 2.0f*p[0]*hr[0] - mc*p[0]*p[0] + dga + SAm[0];
                SA[1] = Ap[1] - p[0]*hr[1] - hr[0]*p[1] - mc*p[0]*p[1] + SAm[1];
                SA[2] = Ap[2] - p[0]*hr[2] - hr[0]*p[2] - mc*p[0]*p[2] + SAm[2];
                SA[3] = Ap[4] - 2.0f*p[1]*hr[1] - mc*p[1]*p[1] + dga + SAm[3];
                SA[4] = Ap[5] - p[1]*hr[2] - hr[1]*p[2] - mc*p[1]*p[2] + SAm[4];
                SA[5] = Ap[8] - 2.0f*p[2]*hr[2] - mc*p[2]*p[2] + dga + SAm[5];
                hc[0] = hr[0] + mc*p[0] + hm[0];
                hc[1] = hr[1] + mc*p[1] + hm[1];
                hc[2] = hr[2] + mc*p[2] + hm[2];
                mc += mm_;
#pragma unroll
                for (int k = i; k < NJ; k++){
                    float tm[3], tf[3], cp[3];
                    mtv3(E, &Fk[k][0], tm); mtv3(E, &Fk[k][3], tf);
                    cross3(p, tf, cp);
                    Fk[k][0]=tm[0]+cp[0]; Fk[k][1]=tm[1]+cp[1]; Fk[k][2]=tm[2]+cp[2];
                    Fk[k][3]=tf[0];       Fk[k][4]=tf[1];       Fk[k][5]=tf[2];
                }
            }
        }
        // ridge + Cholesky factor (diag slots hold 1/L_kk)
#pragma unroll
        for (int i = 0; i < NJ; i++) Mx[MIX(i,i)] += 1e-8f;
#pragma unroll
        for (int k = 0; k < NJ; k++){
            float d = Mx[MIX(k,k)];
#pragma unroll
            for (int j = 0; j < NJ; j++) if (j < k) d -= Mx[MIX(k,j)]*Mx[MIX(k,j)];
            float linv = __builtin_amdgcn_rsqf(d);
            Mx[MIX(k,k)] = linv;
#pragma unroll
            for (int i2 = k+1; i2 < NJ; i2++){
                float s2 = Mx[MIX(i2,k)];
#pragma unroll
                for (int j = 0; j < NJ; j++) if (j < k) s2 -= Mx[MIX(i2,j)]*Mx[MIX(k,j)];
                Mx[MIX(i2,k)] = s2 * linv;
            }
        }
#pragma unroll
        for (int j = 0; j < 28; j++) s_M[lane*MPAD + j] = Mx[j];
    }
    else if (act){
        // =================== RNEA: bias forces ===================
#pragma unroll
        for (int i = 0; i < NJ; i++) rhs[i] = u[e*NJ + i];
        float FF[NJ][6];
        float w[3]  = {0.f,0.f,0.f}, vl[3] = {0.f,0.f,0.f};
        float aw[3] = {0.f,0.f,0.f}, av[3] = {0.f,0.f,GRAVF};
#pragma unroll
        for (int i = 0; i < NJ; i++){
            float Rt[9], a[3], p[3], SAi[6], hi[3], mi;
            loadJ(cst, i, Rt, a, p, SAi, hi, mi);
            float E[9]; makeE(a, Rt, sn[i], cs[i], E);
            float qdi = qd[i];
            float tw[3]; mv3(E, w, tw);
            float nw[3] = { tw[0]+a[0]*qdi, tw[1]+a[1]*qdi, tw[2]+a[2]*qdi };
            float cwp[3]; cross3(w, p, cwp);
            float t1[3] = { vl[0]+cwp[0], vl[1]+cwp[1], vl[2]+cwp[2] };
            float nvl[3]; mv3(E, t1, nvl);
            float taw[3]; mv3(E, aw, taw);
            float cna[3]; cross3(nw, a, cna);
            float naw[3] = { taw[0]+qdi*cna[0], taw[1]+qdi*cna[1], taw[2]+qdi*cna[2] };
            float cap[3]; cross3(aw, p, cap);
            float t2[3] = { av[0]+cap[0], av[1]+cap[1], av[2]+cap[2] };
            float tav[3]; mv3(E, t2, tav);
            float cva[3]; cross3(nvl, a, cva);
            float nav[3] = { tav[0]+qdi*cva[0], tav[1]+qdi*cva[1], tav[2]+qdi*cva[2] };
            float Ivt[3], Iat[3], hxv[3], hxa[3];
            symv(SAi, nw, Ivt);  cross3(hi, nvl, hxv);
            symv(SAi, naw, Iat); cross3(hi, nav, hxa);
#pragma unroll
            for (int k = 0; k < 3; k++){ Ivt[k] += hxv[k]; Iat[k] += hxa[k]; }
            float hxw[3], hxaw[3];
            cross3(hi, nw, hxw); cross3(hi, naw, hxaw);
            float Ivb[3] = { mi*nvl[0]-hxw[0], mi*nvl[1]-hxw[1], mi*nvl[2]-hxw[2] };
            float Iab[3] = { mi*nav[0]-hxaw[0], mi*nav[1]-hxaw[1], mi*nav[2]-hxaw[2] };
            float c1[3], c2[3], c3[3];
            cross3(nw, Ivt, c1); cross3(nvl, Ivb, c2); cross3(nw, Ivb, c3);
            FF[i][0] = Iat[0]+c1[0]+c2[0];
            FF[i][1] = Iat[1]+c1[1]+c2[1];
            FF[i][2] = Iat[2]+c1[2]+c2[2];
            FF[i][3] = Iab[0]+c3[0];
            FF[i][4] = Iab[1]+c3[1];
            FF[i][5] = Iab[2]+c3[2];
#pragma unroll
            for (int k = 0; k < 3; k++){ w[k]=nw[k]; vl[k]=nvl[k]; aw[k]=naw[k]; av[k]=nav[k]; }
        }
        // backward fold: E recomputed (45 VALU) instead of held (63 VGPR)
#pragma unroll
        for (int i = NJ-1; i >= 0; i--){
            float Rt[9], a[3], p[3];
            loadG(cst, i, Rt, a, p);
            rhs[i] -= a[0]*FF[i][0] + a[1]*FF[i][1] + a[2]*FF[i][2];
            if (i > 0){
                float E[9]; makeE(a, Rt, sn[i], cs[i], E);
                float tm[3], tf[3], cp[3];
                mtv3(E, &FF[i][0], tm); mtv3(E, &FF[i][3], tf);
                cross3(p, tf, cp);
                FF[i-1][0]+=tm[0]+cp[0]; FF[i-1][1]+=tm[1]+cp[1]; FF[i-1][2]+=tm[2]+cp[2];
                FF[i-1][3]+=tf[0];       FF[i-1][4]+=tf[1];       FF[i-1][5]+=tf[2];
            }
        }
    }

    __syncthreads();

    if (act && role == 0){
        // =================== triangular solves + integrate ===================
        float Mx[28];
#pragma unroll
        for (int j = 0; j < 28; j++) Mx[j] = s_M[lane*MPAD + j];
        float y[NJ];
#pragma unroll
        for (int i = 0; i < NJ; i++){
            float s2 = rhs[i];
#pragma unroll
            for (int j = 0; j < NJ; j++) if (j < i) s2 -= Mx[MIX(i,j)]*y[j];
            y[i] = s2 * Mx[MIX(i,i)];
        }
        float z[NJ];
#pragma unroll
        for (int i = NJ-1; i >= 0; i--){
            float s2 = y[i];
#pragma unroll
            for (int j = NJ-1; j >= 0; j--) if (j > i) s2 -= Mx[MIX(j,i)]*z[j];
            z[i] = s2 * Mx[MIX(i,i)];
        }
        float o14[14];
#pragma unroll
        for (int i = 0; i < NJ; i++){
            float qdn = qd[i] + DTF*z[i];
            o14[i]      = q[i] + DTF*qdn;
            o14[NJ + i] = qdn;
        }
        float2* o2 = (float2*)(out + e*14);
#pragma unroll
        for (int i = 0; i < 7; i++){ float2 v; v.x = o14[2*i]; v.y = o14[2*i+1]; o2[i] = v; }
    }
}

extern "C" void kernel_launch(void* const* d_in, const int* in_sizes, int n_in,
                              void* d_out, int out_size, void* d_ws, size_t ws_size,
                              hipStream_t stream) {
    const float* x   = (const float*)d_in[0];
    const float* u   = (const float*)d_in[1];
    const float* ax  = (const float*)d_in[2];
    const float* Rt  = (const float*)d_in[3];
    const float* pt  = (const float*)d_in[4];
    const float* Isp = (const float*)d_in[5];
    float* out = (float*)d_out;
    float* cst = (float*)d_ws;   // NJ*CW floats
    int B = in_sizes[0] / 14;
    hipLaunchKernelGGL(panda_prep, dim3(1), dim3(64), 0, stream, ax, Rt, pt, Isp, cst);
    int grid = (B + 63) / 64;
    hipLaunchKernelGGL(panda_step, dim3(grid), dim3(128), 0, stream,
                       x, u, cst, out, B);
}

// Round 9
// 77.719 us; speedup vs baseline: 1.2195x; 1.2195x over previous
//
#include <hip/hip_runtime.h>
#include <math.h>

#define NJ 7
#define DTF 0.01f
#define GRAVF 9.81f
#define MIX(i,j) ((i)*((i)+1)/2 + (j))
#define MPAD 29   // 28 lower-tri floats padded to 29

__device__ __forceinline__ void cross3(const float* a, const float* b, float* o){
    o[0] = a[1]*b[2] - a[2]*b[1];
    o[1] = a[2]*b[0] - a[0]*b[2];
    o[2] = a[0]*b[1] - a[1]*b[0];
}
__device__ __forceinline__ void mv3(const float* E, const float* x, float* y){
    y[0] = E[0]*x[0] + E[1]*x[1] + E[2]*x[2];
    y[1] = E[3]*x[0] + E[4]*x[1] + E[5]*x[2];
    y[2] = E[6]*x[0] + E[7]*x[1] + E[8]*x[2];
}
__device__ __forceinline__ void mtv3(const float* E, const float* x, float* y){
    y[0] = E[0]*x[0] + E[3]*x[1] + E[6]*x[2];
    y[1] = E[1]*x[0] + E[4]*x[1] + E[7]*x[2];
    y[2] = E[2]*x[0] + E[5]*x[1] + E[8]*x[2];
}
__device__ __forceinline__ void symv(const float* S, const float* x, float* y){
    y[0] = S[0]*x[0] + S[1]*x[1] + S[2]*x[2];
    y[1] = S[1]*x[0] + S[3]*x[1] + S[4]*x[2];
    y[2] = S[2]*x[0] + S[4]*x[1] + S[5]*x[2];
}
__device__ __forceinline__ void mm3(const float* A, const float* B, float* o){
#pragma unroll
    for (int r = 0; r < 3; r++)
#pragma unroll
        for (int c = 0; c < 3; c++)
            o[r*3+c] = A[r*3]*B[c] + A[r*3+1]*B[3+c] + A[r*3+2]*B[6+c];
}
// o = E^T X E
__device__ __forceinline__ void congr(const float* E, const float* X, float* o){
    float t[9];
#pragma unroll
    for (int r = 0; r < 3; r++)
#pragma unroll
        for (int c = 0; c < 3; c++)
            t[r*3+c] = E[r]*X[c] + E[3+r]*X[3+c] + E[6+r]*X[6+c];
    mm3(t, E, o);
}
// E_i = R(q_i)^T @ R_tree[i]
__device__ __forceinline__ void makeE(const float* a, const float* __restrict__ Rt,
                                      float s, float c, float* E){
    float omc = 1.0f - c;
    float RT[9];
    RT[0] = c + omc*a[0]*a[0];       RT[1] =  s*a[2] + omc*a[0]*a[1]; RT[2] = -s*a[1] + omc*a[0]*a[2];
    RT[3] = -s*a[2] + omc*a[1]*a[0]; RT[4] = c + omc*a[1]*a[1];       RT[5] =  s*a[0] + omc*a[1]*a[2];
    RT[6] =  s*a[1] + omc*a[2]*a[0]; RT[7] = -s*a[0] + omc*a[2]*a[1]; RT[8] = c + omc*a[2]*a[2];
    float Rl[9];
#pragma unroll
    for (int k = 0; k < 9; k++) Rl[k] = Rt[k];
    mm3(RT, Rl, E);
}
// body spatial-inertia params (wave-uniform scalar loads)
__device__ __forceinline__ void bodyI(const float* __restrict__ g_I, int i,
                                      float* SA, float* h, float& m){
    const float* I6 = g_I + i*36;
    SA[0]=I6[0]; SA[1]=I6[1]; SA[2]=I6[2];
    SA[3]=I6[7]; SA[4]=I6[8]; SA[5]=I6[14];
    h[0]=I6[16]; h[1]=I6[5]; h[2]=I6[9];   // h = (B[2][1], B[0][2], B[1][0])
    m = I6[21];
}
// I^0 = X_{i<-0}^T I X_{i<-0}, X=(Ec,rc)
__device__ __forceinline__ void congrBase(const float* Ec, const float* rc,
                                          const float* SA, const float* h, float m,
                                          float* SA0, float* h0){
    float Af[9] = {SA[0],SA[1],SA[2], SA[1],SA[3],SA[4], SA[2],SA[4],SA[5]};
    float Ap[9]; congr(Ec, Af, Ap);
    float hr[3]; mtv3(Ec, h, hr);
    float hpd = hr[0]*rc[0]+hr[1]*rc[1]+hr[2]*rc[2];
    float ppd = rc[0]*rc[0]+rc[1]*rc[1]+rc[2]*rc[2];
    float dga = 2.0f*hpd + m*ppd;
    SA0[0] = Ap[0] - 2.0f*rc[0]*hr[0] - m*rc[0]*rc[0] + dga;
    SA0[1] = Ap[1] - rc[0]*hr[1] - hr[0]*rc[1] - m*rc[0]*rc[1];
    SA0[2] = Ap[2] - rc[0]*hr[2] - hr[0]*rc[2] - m*rc[0]*rc[2];
    SA0[3] = Ap[4] - 2.0f*rc[1]*hr[1] - m*rc[1]*rc[1] + dga;
    SA0[4] = Ap[5] - rc[1]*hr[2] - hr[1]*rc[2] - m*rc[1]*rc[2];
    SA0[5] = Ap[8] - 2.0f*rc[2]*hr[2] - m*rc[2]*rc[2] + dga;
    h0[0] = hr[0] + m*rc[0];
    h0[1] = hr[1] + m*rc[1];
    h0[2] = hr[2] + m*rc[2];
}

__constant__ float QL_c[NJ] = {-2.9671f,-1.8326f,-2.9671f,-3.1416f,-2.9671f,-0.0873f,-2.9671f};
__constant__ float QU_c[NJ] = { 2.9671f, 1.8326f, 2.9671f, 0.0f,    2.9671f, 3.8223f, 2.9671f};

// Block = 128 = 2 waves on the SAME 64 elements.
// Wave 0: link-frame RNEA (bias -> rhs); then solves + integrate + store.
// Wave 1: BASE-frame CRBA (short critical path) + Cholesky factor -> LDS.
__global__ __launch_bounds__(128)
void panda_step(const float* __restrict__ x, const float* __restrict__ u,
                const float* __restrict__ g_ax, const float* __restrict__ g_Rt,
                const float* __restrict__ g_pt, const float* __restrict__ g_I,
                float* __restrict__ out, int B)
{
    __shared__ float s_M[64*MPAD];

    const int role = threadIdx.x >> 6;      // wave-uniform
    const int lane = threadIdx.x & 63;
    const int e    = blockIdx.x*64 + lane;
    const bool act = (e < B);

    float q[NJ], qd[NJ], sn[NJ], cs[NJ];
    if (act){
        float xl[14];
        const float2* x2 = (const float2*)(x + e*14);
#pragma unroll
        for (int i = 0; i < 7; i++){ float2 v = x2[i]; xl[2*i] = v.x; xl[2*i+1] = v.y; }
#pragma unroll
        for (int i = 0; i < NJ; i++){
            q[i]  = fminf(fmaxf(xl[i], QL_c[i]), QU_c[i]);
            qd[i] = xl[NJ + i];
            __sincosf(q[i], &sn[i], &cs[i]);
        }
    }

    float rhs[NJ];

    if (act && role == 1){
        // ======== CRBA in BASE frame: short serial chain, wide ILP ========
        float Sw[NJ][3], Sv[NJ][3];      // S^0_i
        float SB[NJ][6], hB[NJ][3];      // I^0_i
        float Ec[9], rc[3];
#pragma unroll
        for (int i = 0; i < NJ; i++){
            float a[3] = { g_ax[3*i], g_ax[3*i+1], g_ax[3*i+2] };
            float p[3] = { g_pt[3*i], g_pt[3*i+1], g_pt[3*i+2] };
            float E[9]; makeE(a, g_Rt + 9*i, sn[i], cs[i], E);
            if (i == 0){
#pragma unroll
                for (int k = 0; k < 9; k++) Ec[k] = E[k];
                rc[0]=p[0]; rc[1]=p[1]; rc[2]=p[2];
            } else {
                float t3[3]; mtv3(Ec, p, t3);
                rc[0]+=t3[0]; rc[1]+=t3[1]; rc[2]+=t3[2];
                float En[9]; mm3(E, Ec, En);
#pragma unroll
                for (int k = 0; k < 9; k++) Ec[k] = En[k];
            }
            float sh[3]; mtv3(Ec, a, sh);
            float cb[3]; cross3(rc, sh, cb);
#pragma unroll
            for (int k = 0; k < 3; k++){ Sw[i][k]=sh[k]; Sv[i][k]=cb[k]; }
            float SAb[6], hb[3], mb; bodyI(g_I, i, SAb, hb, mb);
            congrBase(Ec, rc, SAb, hb, mb, &SB[i][0], &hB[i][0]);
        }
        // suffix composite inertia + M rows (all dot-products independent)
        float IcA[6] = {0,0,0,0,0,0}, Ich[3] = {0,0,0}, Icm = 0.f;
        float Mx[28];
#pragma unroll
        for (int i = NJ-1; i >= 0; i--){
#pragma unroll
            for (int k = 0; k < 6; k++) IcA[k] += SB[i][k];
#pragma unroll
            for (int k = 0; k < 3; k++) Ich[k] += hB[i][k];
            Icm += g_I[i*36 + 21];
            float Ft[3], Fb[3], t1[3], t2[3];
            symv(IcA, &Sw[i][0], Ft);
            cross3(Ich, &Sv[i][0], t1);
#pragma unroll
            for (int k = 0; k < 3; k++) Ft[k] += t1[k];
            cross3(Ich, &Sw[i][0], t2);
#pragma unroll
            for (int k = 0; k < 3; k++) Fb[k] = Icm*Sv[i][k] - t2[k];
#pragma unroll
            for (int j = 0; j < NJ; j++) if (j <= i){
                Mx[MIX(i,j)] = Sw[j][0]*Ft[0] + Sw[j][1]*Ft[1] + Sw[j][2]*Ft[2]
                             + Sv[j][0]*Fb[0] + Sv[j][1]*Fb[1] + Sv[j][2]*Fb[2];
            }
        }
        // ridge + Cholesky factor (diag slots hold 1/L_kk)
#pragma unroll
        for (int i = 0; i < NJ; i++) Mx[MIX(i,i)] += 1e-8f;
#pragma unroll
        for (int k = 0; k < NJ; k++){
            float d = Mx[MIX(k,k)];
#pragma unroll
            for (int j = 0; j < NJ; j++) if (j < k) d -= Mx[MIX(k,j)]*Mx[MIX(k,j)];
            float linv = __builtin_amdgcn_rsqf(d);
            Mx[MIX(k,k)] = linv;
#pragma unroll
            for (int i2 = k+1; i2 < NJ; i2++){
                float s2 = Mx[MIX(i2,k)];
#pragma unroll
                for (int j = 0; j < NJ; j++) if (j < k) s2 -= Mx[MIX(i2,j)]*Mx[MIX(k,j)];
                Mx[MIX(i2,k)] = s2 * linv;
            }
        }
#pragma unroll
        for (int j = 0; j < 28; j++) s_M[lane*MPAD + j] = Mx[j];
    }
    else if (act){
        // ======== RNEA in LINK frame (R5 structure, E kept in registers) ========
#pragma unroll
        for (int i = 0; i < NJ; i++) rhs[i] = u[e*NJ + i];
        float Earr[NJ][9];
        float FF[NJ][6];
        float w[3]  = {0.f,0.f,0.f}, vl[3] = {0.f,0.f,0.f};
        float aw[3] = {0.f,0.f,0.f}, av[3] = {0.f,0.f,GRAVF};
#pragma unroll
        for (int i = 0; i < NJ; i++){
            float a[3] = { g_ax[3*i], g_ax[3*i+1], g_ax[3*i+2] };
            float p[3] = { g_pt[3*i], g_pt[3*i+1], g_pt[3*i+2] };
            float* E = &Earr[i][0];
            makeE(a, g_Rt + 9*i, sn[i], cs[i], E);
            float qdi = qd[i];
            float tw[3]; mv3(E, w, tw);
            float nw[3] = { tw[0]+a[0]*qdi, tw[1]+a[1]*qdi, tw[2]+a[2]*qdi };
            float cwp[3]; cross3(w, p, cwp);
            float t1[3] = { vl[0]+cwp[0], vl[1]+cwp[1], vl[2]+cwp[2] };
            float nvl[3]; mv3(E, t1, nvl);
            float taw[3]; mv3(E, aw, taw);
            float cna[3]; cross3(nw, a, cna);
            float naw[3] = { taw[0]+qdi*cna[0], taw[1]+qdi*cna[1], taw[2]+qdi*cna[2] };
            float cap[3]; cross3(aw, p, cap);
            float t2[3] = { av[0]+cap[0], av[1]+cap[1], av[2]+cap[2] };
            float tav[3]; mv3(E, t2, tav);
            float cva[3]; cross3(nvl, a, cva);
            float nav[3] = { tav[0]+qdi*cva[0], tav[1]+qdi*cva[1], tav[2]+qdi*cva[2] };
            float SAi[6], hi[3], mi; bodyI(g_I, i, SAi, hi, mi);
            float Ivt[3], Iat[3], hxv[3], hxa[3];
            symv(SAi, nw, Ivt);  cross3(hi, nvl, hxv);
            symv(SAi, naw, Iat); cross3(hi, nav, hxa);
#pragma unroll
            for (int k = 0; k < 3; k++){ Ivt[k] += hxv[k]; Iat[k] += hxa[k]; }
            float hxw[3], hxaw[3];
            cross3(hi, nw, hxw); cross3(hi, naw, hxaw);
            float Ivb[3] = { mi*nvl[0]-hxw[0], mi*nvl[1]-hxw[1], mi*nvl[2]-hxw[2] };
            float Iab[3] = { mi*nav[0]-hxaw[0], mi*nav[1]-hxaw[1], mi*nav[2]-hxaw[2] };
            float c1[3], c2[3], c3[3];
            cross3(nw, Ivt, c1); cross3(nvl, Ivb, c2); cross3(nw, Ivb, c3);
            FF[i][0] = Iat[0]+c1[0]+c2[0];
            FF[i][1] = Iat[1]+c1[1]+c2[1];
            FF[i][2] = Iat[2]+c1[2]+c2[2];
            FF[i][3] = Iab[0]+c3[0];
            FF[i][4] = Iab[1]+c3[1];
            FF[i][5] = Iab[2]+c3[2];
#pragma unroll
            for (int k = 0; k < 3; k++){ w[k]=nw[k]; vl[k]=nvl[k]; aw[k]=naw[k]; av[k]=nav[k]; }
        }
        // backward fold (E from registers)
#pragma unroll
        for (int i = NJ-1; i >= 0; i--){
            float a[3] = { g_ax[3*i], g_ax[3*i+1], g_ax[3*i+2] };
            rhs[i] -= a[0]*FF[i][0] + a[1]*FF[i][1] + a[2]*FF[i][2];
            if (i > 0){
                float p[3] = { g_pt[3*i], g_pt[3*i+1], g_pt[3*i+2] };
                const float* E = &Earr[i][0];
                float tm[3], tf[3], cp[3];
                mtv3(E, &FF[i][0], tm); mtv3(E, &FF[i][3], tf);
                cross3(p, tf, cp);
                FF[i-1][0]+=tm[0]+cp[0]; FF[i-1][1]+=tm[1]+cp[1]; FF[i-1][2]+=tm[2]+cp[2];
                FF[i-1][3]+=tf[0];       FF[i-1][4]+=tf[1];       FF[i-1][5]+=tf[2];
            }
        }
    }

    __syncthreads();

    if (act && role == 0){
        // ======== triangular solves + integrate + store ========
        float Mx[28];
#pragma unroll
        for (int j = 0; j < 28; j++) Mx[j] = s_M[lane*MPAD + j];
        float y[NJ];
#pragma unroll
        for (int i = 0; i < NJ; i++){
            float s2 = rhs[i];
#pragma unroll
            for (int j = 0; j < NJ; j++) if (j < i) s2 -= Mx[MIX(i,j)]*y[j];
            y[i] = s2 * Mx[MIX(i,i)];
        }
        float z[NJ];
#pragma unroll
        for (int i = NJ-1; i >= 0; i--){
            float s2 = y[i];
#pragma unroll
            for (int j = NJ-1; j >= 0; j--) if (j > i) s2 -= Mx[MIX(j,i)]*z[j];
            z[i] = s2 * Mx[MIX(i,i)];
        }
        float o14[14];
#pragma unroll
        for (int i = 0; i < NJ; i++){
            float qdn = qd[i] + DTF*z[i];
            o14[i]      = q[i] + DTF*qdn;
            o14[NJ + i] = qdn;
        }
        float2* o2 = (float2*)(out + e*14);
#pragma unroll
        for (int i = 0; i < 7; i++){ float2 v; v.x = o14[2*i]; v.y = o14[2*i+1]; o2[i] = v; }
    }
}

extern "C" void kernel_launch(void* const* d_in, const int* in_sizes, int n_in,
                              void* d_out, int out_size, void* d_ws, size_t ws_size,
                              hipStream_t stream) {
    const float* x   = (const float*)d_in[0];
    const float* u   = (const float*)d_in[1];
    const float* ax  = (const float*)d_in[2];
    const float* Rt  = (const float*)d_in[3];
    const float* pt  = (const float*)d_in[4];
    const float* Isp = (const float*)d_in[5];
    float* out = (float*)d_out;
    int B = in_sizes[0] / 14;
    int grid = (B + 63) / 64;
    hipLaunchKernelGGL(panda_step, dim3(grid), dim3(128), 0, stream,
                       x, u, ax, Rt, pt, Isp, out, B);
}

// Round 10
// 77.283 us; speedup vs baseline: 1.2264x; 1.0056x over previous
//
#include <hip/hip_runtime.h>
#include <math.h>

#define NJ 7
#define DTF 0.01f
#define GRAVF 9.81f
#define MIX(i,j) ((i)*((i)+1)/2 + (j))
#define MPAD 29   // s_M stride (gcd(29,32)=1 -> free 2-way)
#define FSTR 43   // per-lane F stride (gcd(43,32)=1)
#define SNC  15   // sn/cs stride (gcd(15,32)=1)
#define QST  9    // qd/rhs stride (gcd(9,32)=1)

__device__ __forceinline__ void cross3(const float* a, const float* b, float* o){
    o[0] = a[1]*b[2] - a[2]*b[1];
    o[1] = a[2]*b[0] - a[0]*b[2];
    o[2] = a[0]*b[1] - a[1]*b[0];
}
__device__ __forceinline__ void mv3(const float* E, const float* x, float* y){
    y[0] = E[0]*x[0] + E[1]*x[1] + E[2]*x[2];
    y[1] = E[3]*x[0] + E[4]*x[1] + E[5]*x[2];
    y[2] = E[6]*x[0] + E[7]*x[1] + E[8]*x[2];
}
__device__ __forceinline__ void mtv3(const float* E, const float* x, float* y){
    y[0] = E[0]*x[0] + E[3]*x[1] + E[6]*x[2];
    y[1] = E[1]*x[0] + E[4]*x[1] + E[7]*x[2];
    y[2] = E[2]*x[0] + E[5]*x[1] + E[8]*x[2];
}
__device__ __forceinline__ void symv(const float* S, const float* x, float* y){
    y[0] = S[0]*x[0] + S[1]*x[1] + S[2]*x[2];
    y[1] = S[1]*x[0] + S[3]*x[1] + S[4]*x[2];
    y[2] = S[2]*x[0] + S[4]*x[1] + S[5]*x[2];
}
__device__ __forceinline__ void mm3(const float* A, const float* B, float* o){
#pragma unroll
    for (int r = 0; r < 3; r++)
#pragma unroll
        for (int c = 0; c < 3; c++)
            o[r*3+c] = A[r*3]*B[c] + A[r*3+1]*B[3+c] + A[r*3+2]*B[6+c];
}
// o = E^T X E
__device__ __forceinline__ void congr(const float* E, const float* X, float* o){
    float t[9];
#pragma unroll
    for (int r = 0; r < 3; r++)
#pragma unroll
        for (int c = 0; c < 3; c++)
            t[r*3+c] = E[r]*X[c] + E[3+r]*X[3+c] + E[6+r]*X[6+c];
    mm3(t, E, o);
}
// E_i = R(q_i)^T @ R_tree[i]
__device__ __forceinline__ void makeE(const float* a, const float* __restrict__ Rt,
                                      float s, float c, float* E){
    float omc = 1.0f - c;
    float RT[9];
    RT[0] = c + omc*a[0]*a[0];       RT[1] =  s*a[2] + omc*a[0]*a[1]; RT[2] = -s*a[1] + omc*a[0]*a[2];
    RT[3] = -s*a[2] + omc*a[1]*a[0]; RT[4] = c + omc*a[1]*a[1];       RT[5] =  s*a[0] + omc*a[1]*a[2];
    RT[6] =  s*a[1] + omc*a[2]*a[0]; RT[7] = -s*a[0] + omc*a[2]*a[1]; RT[8] = c + omc*a[2]*a[2];
    float Rl[9];
#pragma unroll
    for (int k = 0; k < 9; k++) Rl[k] = Rt[k];
    mm3(RT, Rl, E);
}
// body spatial-inertia params (wave-uniform scalar loads)
__device__ __forceinline__ void bodyI(const float* __restrict__ g_I, int i,
                                      float* SA, float* h, float& m){
    const float* I6 = g_I + i*36;
    SA[0]=I6[0]; SA[1]=I6[1]; SA[2]=I6[2];
    SA[3]=I6[7]; SA[4]=I6[8]; SA[5]=I6[14];
    h[0]=I6[16]; h[1]=I6[5]; h[2]=I6[9];
    m = I6[21];
}

__constant__ float QL_c[NJ] = {-2.9671f,-1.8326f,-2.9671f,-3.1416f,-2.9671f,-0.0873f,-2.9671f};
__constant__ float QU_c[NJ] = { 2.9671f, 1.8326f, 2.9671f, 0.0f,    2.9671f, 3.8223f, 2.9671f};

// Block = 128 = 2 waves on the SAME 64 elements. Rolled per-joint loops keep
// code ~10 KB (I$-resident). Dynamic per-joint state lives in LDS.
// Wave 0: link-frame RNEA -> rhs; after barrier: solves + integrate + store.
// Wave 1: link-frame CRBA -> M -> Cholesky factor -> s_M.
__global__ __launch_bounds__(128)
void panda_step(const float* __restrict__ x, const float* __restrict__ u,
                const float* __restrict__ g_ax, const float* __restrict__ g_Rt,
                const float* __restrict__ g_pt, const float* __restrict__ g_I,
                float* __restrict__ out, int B)
{
    __shared__ float s_M[64*MPAD];     // 7424 B
    __shared__ float s_F[2*64*FSTR];   // 22016 B (role0: FF, role1: Fk)
    __shared__ float s_snc[64*SNC];    // 3840 B (sn[0:7), cs[7:14))
    __shared__ float s_qd[64*QST];     // 2304 B
    __shared__ float s_rhs[64*QST];    // 2304 B

    const int role = threadIdx.x >> 6;      // wave-uniform
    const int lane = threadIdx.x & 63;
    const int e    = blockIdx.x*64 + lane;
    const bool act = (e < B);

    float q[NJ], qd[NJ];
    if (act && role == 0){
        float xl[14];
        const float2* x2 = (const float2*)(x + e*14);
#pragma unroll
        for (int i = 0; i < 7; i++){ float2 v = x2[i]; xl[2*i] = v.x; xl[2*i+1] = v.y; }
#pragma unroll
        for (int i = 0; i < NJ; i++){
            q[i]  = fminf(fmaxf(xl[i], QL_c[i]), QU_c[i]);
            qd[i] = xl[NJ + i];
            float s, c; __sincosf(q[i], &s, &c);
            s_snc[lane*SNC + i]     = s;
            s_snc[lane*SNC + 7 + i] = c;
            s_qd[lane*QST + i]      = qd[i];
            s_rhs[lane*QST + i]     = u[e*NJ + i];
        }
    }
    __syncthreads();   // publish sn/cs/qd/rhs

    if (act && role == 1){
        // =================== CRBA (rolled) + Cholesky ===================
        float* Fb = &s_F[64*FSTR + lane*FSTR];
        float SA[6], hc[3], mc;
        bodyI(g_I, 6, SA, hc, mc);
#pragma unroll 1
        for (int i = NJ-1; i >= 0; --i){
            float a[3] = { g_ax[3*i], g_ax[3*i+1], g_ax[3*i+2] };
            float p[3] = { g_pt[3*i], g_pt[3*i+1], g_pt[3*i+2] };
            // F_i = [SA a ; a x hc]
            float Ft[3]; symv(SA, a, Ft);
            Fb[i*6+0]=Ft[0]; Fb[i*6+1]=Ft[1]; Fb[i*6+2]=Ft[2];
            Fb[i*6+3] = a[1]*hc[2] - a[2]*hc[1];
            Fb[i*6+4] = a[2]*hc[0] - a[0]*hc[2];
            Fb[i*6+5] = a[0]*hc[1] - a[1]*hc[0];
            // M column i
#pragma unroll 1
            for (int k = i; k < NJ; ++k){
                float f0=Fb[k*6], f1=Fb[k*6+1], f2=Fb[k*6+2];
                s_M[lane*MPAD + k*(k+1)/2 + i] = a[0]*f0 + a[1]*f1 + a[2]*f2;
            }
            if (i > 0){
                float snv = s_snc[lane*SNC+i], csv = s_snc[lane*SNC+7+i];
                float E[9]; makeE(a, g_Rt + 9*i, snv, csv, E);
                float SAm[6], hm[3], mm_;
                bodyI(g_I, i-1, SAm, hm, mm_);
                float Af[9] = {SA[0],SA[1],SA[2], SA[1],SA[3],SA[4], SA[2],SA[4],SA[5]};
                float Ap[9]; congr(E, Af, Ap);
                float hr[3]; mtv3(E, hc, hr);
                float hpd = hr[0]*p[0]+hr[1]*p[1]+hr[2]*p[2];
                float ppd = p[0]*p[0]+p[1]*p[1]+p[2]*p[2];
                float dga = 2.0f*hpd + mc*ppd;
                SA[0] = Ap[0] - 2.0f*p[0]*hr[0] - mc*p[0]*p[0] + dga + SAm[0];
                SA[1] = Ap[1] - p[0]*hr[1] - hr[0]*p[1] - mc*p[0]*p[1] + SAm[1];
                SA[2] = Ap[2] - p[0]*hr[2] - hr[0]*p[2] - mc*p[0]*p[2] + SAm[2];
                SA[3] = Ap[4] - 2.0f*p[1]*hr[1] - mc*p[1]*p[1] + dga + SAm[3];
                SA[4] = Ap[5] - p[1]*hr[2] - hr[1]*p[2] - mc*p[1]*p[2] + SAm[4];
                SA[5] = Ap[8] - 2.0f*p[2]*hr[2] - mc*p[2]*p[2] + dga + SAm[5];
                hc[0] = hr[0] + mc*p[0] + hm[0];
                hc[1] = hr[1] + mc*p[1] + hm[1];
                hc[2] = hr[2] + mc*p[2] + hm[2];
                mc += mm_;
                // transform active F_k into frame i-1
#pragma unroll 1
                for (int k = i; k < NJ; ++k){
                    float ft[3] = {Fb[k*6+0], Fb[k*6+1], Fb[k*6+2]};
                    float fb[3] = {Fb[k*6+3], Fb[k*6+4], Fb[k*6+5]};
                    float tm[3], tf[3], cp[3];
                    mtv3(E, ft, tm); mtv3(E, fb, tf);
                    cross3(p, tf, cp);
                    Fb[k*6+0]=tm[0]+cp[0]; Fb[k*6+1]=tm[1]+cp[1]; Fb[k*6+2]=tm[2]+cp[2];
                    Fb[k*6+3]=tf[0];       Fb[k*6+4]=tf[1];       Fb[k*6+5]=tf[2];
                }
            }
        }
        // ridge + Cholesky factor in registers (small unrolled region)
        float Mx[28];
#pragma unroll
        for (int j = 0; j < 28; j++) Mx[j] = s_M[lane*MPAD + j];
#pragma unroll
        for (int i = 0; i < NJ; i++) Mx[MIX(i,i)] += 1e-8f;
#pragma unroll
        for (int k = 0; k < NJ; k++){
            float d = Mx[MIX(k,k)];
#pragma unroll
            for (int j = 0; j < NJ; j++) if (j < k) d -= Mx[MIX(k,j)]*Mx[MIX(k,j)];
            float linv = __builtin_amdgcn_rsqf(d);
            Mx[MIX(k,k)] = linv;
#pragma unroll
            for (int i2 = k+1; i2 < NJ; i2++){
                float s2 = Mx[MIX(i2,k)];
#pragma unroll
                for (int j = 0; j < NJ; j++) if (j < k) s2 -= Mx[MIX(i2,j)]*Mx[MIX(k,j)];
                Mx[MIX(i2,k)] = s2 * linv;
            }
        }
#pragma unroll
        for (int j = 0; j < 28; j++) s_M[lane*MPAD + j] = Mx[j];
    }
    else if (act){
        // =================== RNEA (rolled) ===================
        float* Fb = &s_F[lane*FSTR];
        float w[3]  = {0.f,0.f,0.f}, vl[3] = {0.f,0.f,0.f};
        float aw[3] = {0.f,0.f,0.f}, av[3] = {0.f,0.f,GRAVF};
#pragma unroll 1
        for (int i = 0; i < NJ; ++i){
            float a[3] = { g_ax[3*i], g_ax[3*i+1], g_ax[3*i+2] };
            float p[3] = { g_pt[3*i], g_pt[3*i+1], g_pt[3*i+2] };
            float snv = s_snc[lane*SNC+i], csv = s_snc[lane*SNC+7+i];
            float qdi = s_qd[lane*QST+i];
            float E[9]; makeE(a, g_Rt + 9*i, snv, csv, E);
            float tw[3]; mv3(E, w, tw);
            float nw[3] = { tw[0]+a[0]*qdi, tw[1]+a[1]*qdi, tw[2]+a[2]*qdi };
            float cwp[3]; cross3(w, p, cwp);
            float t1[3] = { vl[0]+cwp[0], vl[1]+cwp[1], vl[2]+cwp[2] };
            float nvl[3]; mv3(E, t1, nvl);
            float taw[3]; mv3(E, aw, taw);
            float cna[3]; cross3(nw, a, cna);
            float naw[3] = { taw[0]+qdi*cna[0], taw[1]+qdi*cna[1], taw[2]+qdi*cna[2] };
            float cap[3]; cross3(aw, p, cap);
            float t2[3] = { av[0]+cap[0], av[1]+cap[1], av[2]+cap[2] };
            float tav[3]; mv3(E, t2, tav);
            float cva[3]; cross3(nvl, a, cva);
            float nav[3] = { tav[0]+qdi*cva[0], tav[1]+qdi*cva[1], tav[2]+qdi*cva[2] };
            float SAi[6], hi[3], mi; bodyI(g_I, i, SAi, hi, mi);
            float Ivt[3], Iat[3], hxv[3], hxa[3];
            symv(SAi, nw, Ivt);  cross3(hi, nvl, hxv);
            symv(SAi, naw, Iat); cross3(hi, nav, hxa);
#pragma unroll
            for (int k = 0; k < 3; k++){ Ivt[k] += hxv[k]; Iat[k] += hxa[k]; }
            float hxw[3], hxaw[3];
            cross3(hi, nw, hxw); cross3(hi, naw, hxaw);
            float Ivb[3] = { mi*nvl[0]-hxw[0], mi*nvl[1]-hxw[1], mi*nvl[2]-hxw[2] };
            float Iab[3] = { mi*nav[0]-hxaw[0], mi*nav[1]-hxaw[1], mi*nav[2]-hxaw[2] };
            float c1[3], c2[3], c3[3];
            cross3(nw, Ivt, c1); cross3(nvl, Ivb, c2); cross3(nw, Ivb, c3);
            Fb[i*6+0] = Iat[0]+c1[0]+c2[0];
            Fb[i*6+1] = Iat[1]+c1[1]+c2[1];
            Fb[i*6+2] = Iat[2]+c1[2]+c2[2];
            Fb[i*6+3] = Iab[0]+c3[0];
            Fb[i*6+4] = Iab[1]+c3[1];
            Fb[i*6+5] = Iab[2]+c3[2];
#pragma unroll
            for (int k = 0; k < 3; k++){ w[k]=nw[k]; vl[k]=nvl[k]; aw[k]=naw[k]; av[k]=nav[k]; }
        }
        // backward fold (rolled; E recomputed, ~60 VALU/joint)
#pragma unroll 1
        for (int i = NJ-1; i >= 0; --i){
            float a[3] = { g_ax[3*i], g_ax[3*i+1], g_ax[3*i+2] };
            float f0=Fb[i*6+0], f1=Fb[i*6+1], f2=Fb[i*6+2];
            s_rhs[lane*QST+i] -= a[0]*f0 + a[1]*f1 + a[2]*f2;
            if (i > 0){
                float p[3] = { g_pt[3*i], g_pt[3*i+1], g_pt[3*i+2] };
                float snv = s_snc[lane*SNC+i], csv = s_snc[lane*SNC+7+i];
                float E[9]; makeE(a, g_Rt + 9*i, snv, csv, E);
                float ftop[3] = {f0, f1, f2};
                float fbot[3] = {Fb[i*6+3], Fb[i*6+4], Fb[i*6+5]};
                float tm[3], tf[3], cp[3];
                mtv3(E, ftop, tm); mtv3(E, fbot, tf);
                cross3(p, tf, cp);
                Fb[(i-1)*6+0] += tm[0]+cp[0];
                Fb[(i-1)*6+1] += tm[1]+cp[1];
                Fb[(i-1)*6+2] += tm[2]+cp[2];
                Fb[(i-1)*6+3] += tf[0];
                Fb[(i-1)*6+4] += tf[1];
                Fb[(i-1)*6+5] += tf[2];
            }
        }
    }

    __syncthreads();

    if (act && role == 0){
        // ======== triangular solves + integrate + store ========
        float Mx[28];
#pragma unroll
        for (int j = 0; j < 28; j++) Mx[j] = s_M[lane*MPAD + j];
        float rhs[NJ];
#pragma unroll
        for (int i = 0; i < NJ; i++) rhs[i] = s_rhs[lane*QST + i];
        float y[NJ];
#pragma unroll
        for (int i = 0; i < NJ; i++){
            float s2 = rhs[i];
#pragma unroll
            for (int j = 0; j < NJ; j++) if (j < i) s2 -= Mx[MIX(i,j)]*y[j];
            y[i] = s2 * Mx[MIX(i,i)];
        }
        float z[NJ];
#pragma unroll
        for (int i = NJ-1; i >= 0; i--){
            float s2 = y[i];
#pragma unroll
            for (int j = NJ-1; j >= 0; j--) if (j > i) s2 -= Mx[MIX(j,i)]*z[j];
            z[i] = s2 * Mx[MIX(i,i)];
        }
        float o14[14];
#pragma unroll
        for (int i = 0; i < NJ; i++){
            float qdn = qd[i] + DTF*z[i];
            o14[i]      = q[i] + DTF*qdn;
            o14[NJ + i] = qdn;
        }
        float2* o2 = (float2*)(out + e*14);
#pragma unroll
        for (int i = 0; i < 7; i++){ float2 v; v.x = o14[2*i]; v.y = o14[2*i+1]; o2[i] = v; }
    }
}

extern "C" void kernel_launch(void* const* d_in, const int* in_sizes, int n_in,
                              void* d_out, int out_size, void* d_ws, size_t ws_size,
                              hipStream_t stream) {
    const float* x   = (const float*)d_in[0];
    const float* u   = (const float*)d_in[1];
    const float* ax  = (const float*)d_in[2];
    const float* Rt  = (const float*)d_in[3];
    const float* pt  = (const float*)d_in[4];
    const float* Isp = (const float*)d_in[5];
    float* out = (float*)d_out;
    int B = in_sizes[0] / 14;
    int grid = (B + 63) / 64;
    hipLaunchKernelGGL(panda_step, dim3(grid), dim3(128), 0, stream,
                       x, u, ax, Rt, pt, Isp, out, B);
}